// Round 1
// baseline (394.295 us; speedup 1.0000x reference)
//
#include <hip/hip_runtime.h>
#include <hip/hip_bf16.h>

#define N_NODES 8192
#define E_EDGES 262144
#define R_REL   2
#define F_FEAT  111
#define D_EMB   32
#define H_HID   256
#define C_CLS   15

// ---------------- K2: X0 = x_note @ W_embed + b_embed ----------------
__global__ void k_embed(const float* __restrict__ x_note, const float* __restrict__ W,
                        const float* __restrict__ b, float* __restrict__ X0) {
    __shared__ float Ws[F_FEAT * D_EMB];
    for (int i = threadIdx.x; i < F_FEAT * D_EMB; i += blockDim.x) Ws[i] = W[i];
    __syncthreads();
    int tid = blockIdx.x * blockDim.x + threadIdx.x;   // 8192*32 threads
    int n = tid >> 5, d = tid & 31;
    const float* xr = x_note + n * F_FEAT;
    float acc = b[d];
    for (int f = 0; f < F_FEAT; ++f) acc += xr[f] * Ws[f * D_EMB + d];
    X0[n * D_EMB + d] = acc;
}

// ---------------- K3: mean-agg scatter (raw edges, duplicates count) ----------------
__global__ void k_scatter(const int* __restrict__ edges, const float* __restrict__ X0,
                          float* __restrict__ msg, int* __restrict__ cnt) {
    int tid = blockIdx.x * blockDim.x + threadIdx.x;   // R*E*32 threads
    int g = tid >> 5, lane = tid & 31;
    int r = g / E_EDGES, e = g - r * E_EDGES;
    int src = edges[(r * 2) * E_EDGES + e];
    int dst = edges[(r * 2 + 1) * E_EDGES + e];
    atomicAdd(&msg[(r * N_NODES + dst) * D_EMB + lane], X0[src * D_EMB + lane]);
    if (lane == 0) atomicAdd(&cnt[r * N_NODES + dst], 1);
}

// ---------------- K4: dedup ownership flags + per-src degree ----------------
__global__ void k_flags(const int* __restrict__ edges, unsigned int* __restrict__ bitmap,
                        unsigned char* __restrict__ flags, int* __restrict__ deg) {
    int i = blockIdx.x * blockDim.x + threadIdx.x;     // R*E threads
    int r = i / E_EDGES, e = i - r * E_EDGES;
    int src = edges[(r * 2) * E_EDGES + e];
    int dst = edges[(r * 2 + 1) * E_EDGES + e];
    unsigned int bit = (unsigned int)(src * N_NODES + dst);   // < 2^26
    unsigned int w = (unsigned int)r * (N_NODES * (N_NODES / 32)) + (bit >> 5);
    unsigned int m = 1u << (bit & 31);
    unsigned int old = atomicOr(&bitmap[w], m);
    int own = (old & m) ? 0 : 1;
    flags[i] = (unsigned char)own;
    if (own) atomicAdd(&deg[r * N_NODES + src], 1);
}

// ---------------- K5: exclusive scan of deg -> rowptr (one block per relation) ----------------
__global__ void k_scan(const int* __restrict__ deg, int* __restrict__ rowptr) {
    int r = blockIdx.x;
    __shared__ int part[1024];
    int t = threadIdx.x;
    int base = t * 8;
    int local[8];
    int s = 0;
    #pragma unroll
    for (int i = 0; i < 8; ++i) { local[i] = s; s += deg[r * N_NODES + base + i]; }
    part[t] = s;
    __syncthreads();
    for (int off = 1; off < 1024; off <<= 1) {
        int v = (t >= off) ? part[t - off] : 0;
        __syncthreads();
        if (t >= off) part[t] += v;
        __syncthreads();
    }
    int pre = (t > 0) ? part[t - 1] : 0;
    #pragma unroll
    for (int i = 0; i < 8; ++i) rowptr[r * (N_NODES + 1) + base + i] = pre + local[i];
    if (t == 1023) rowptr[r * (N_NODES + 1) + N_NODES] = part[1023];
}

// ---------------- K6: CSR column scatter (deduped edges only) ----------------
__global__ void k_csr(const int* __restrict__ edges, const unsigned char* __restrict__ flags,
                      const int* __restrict__ rowptr, int* __restrict__ cursor,
                      int* __restrict__ col) {
    int i = blockIdx.x * blockDim.x + threadIdx.x;     // R*E threads
    if (!flags[i]) return;
    int r = i / E_EDGES, e = i - r * E_EDGES;
    int src = edges[(r * 2) * E_EDGES + e];
    int dst = edges[(r * 2 + 1) * E_EDGES + e];
    int pos = rowptr[r * (N_NODES + 1) + src] + atomicAdd(&cursor[r * N_NODES + src], 1);
    col[r * E_EDGES + pos] = dst;
}

// ---------------- K7: H1 = relu(X0*(Ws0+Ws1) + mean0*Wn0 + mean1*Wn1 + b0+b1) ----------------
__global__ void k_gnn(const float* __restrict__ X0, const float* __restrict__ msg,
                      const int* __restrict__ cnt, const float* __restrict__ Wself,
                      const float* __restrict__ Wneigh, const float* __restrict__ bg,
                      float* __restrict__ H1) {
    int n = blockIdx.x;
    __shared__ float xin[3 * D_EMB];
    int t = threadIdx.x;
    if (t < D_EMB) {
        xin[t] = X0[n * D_EMB + t];
    } else if (t < 2 * D_EMB) {
        int d = t - D_EMB;
        int c = cnt[0 * N_NODES + n]; float cf = (float)(c > 0 ? c : 1);
        xin[t] = msg[(0 * N_NODES + n) * D_EMB + d] / cf;
    } else if (t < 3 * D_EMB) {
        int d = t - 2 * D_EMB;
        int c = cnt[1 * N_NODES + n]; float cf = (float)(c > 0 ? c : 1);
        xin[t] = msg[(1 * N_NODES + n) * D_EMB + d] / cf;
    }
    __syncthreads();
    int h = t;
    float acc = bg[h] + bg[H_HID + h];
    #pragma unroll 4
    for (int d = 0; d < D_EMB; ++d) {
        acc += xin[d] * (Wself[d * H_HID + h] + Wself[D_EMB * H_HID + d * H_HID + h]);
        acc += xin[D_EMB + d] * Wneigh[d * H_HID + h];
        acc += xin[2 * D_EMB + d] * Wneigh[D_EMB * H_HID + d * H_HID + h];
    }
    H1[n * H_HID + h] = fmaxf(acc, 0.f);
}

// ---------------- K8: y = (adj0 + adj1) @ H1 via CSR ----------------
__global__ void k_spmm(const int* __restrict__ rowptr, const int* __restrict__ col,
                       const float* __restrict__ H1, float* __restrict__ y) {
    int n = blockIdx.x, h = threadIdx.x;
    float acc = 0.f;
    for (int r = 0; r < R_REL; ++r) {
        int s = rowptr[r * (N_NODES + 1) + n], e2 = rowptr[r * (N_NODES + 1) + n + 1];
        const int* cr = col + r * E_EDGES;
        for (int idx = s; idx < e2; ++idx) acc += H1[cr[idx] * H_HID + h];
    }
    y[n * H_HID + h] = acc;
}

// ---------------- K9: S1 = softmax(y @ W_s1) ----------------
__global__ void k_softmax1(const float* __restrict__ y, const float* __restrict__ Ws,
                           float* __restrict__ S1) {
    int tid = blockIdx.x * blockDim.x + threadIdx.x;   // 8192*16 threads
    int n = tid >> 4, c = tid & 15;
    float logit = -1e30f;
    if (c < C_CLS) {
        float acc = 0.f;
        const float* yr = y + n * H_HID;
        for (int h = 0; h < H_HID; ++h) acc += yr[h] * Ws[h * C_CLS + c];
        logit = acc;
    }
    float m = logit;
    for (int off = 8; off; off >>= 1) m = fmaxf(m, __shfl_xor(m, off, 16));
    float e = (c < C_CLS) ? expf(logit - m) : 0.f;
    float ssum = e;
    for (int off = 8; off; off >>= 1) ssum += __shfl_xor(ssum, off, 16);
    if (c < C_CLS) S1[n * C_CLS + c] = e / ssum;
}

// ---------------- K10: xp = S1^T @ H1 ----------------
__global__ void k_xp(const float* __restrict__ S1, const float* __restrict__ H1,
                     float* __restrict__ xp) {
    int h = threadIdx.x;
    int base = blockIdx.x * 64;
    float acc[C_CLS];
    #pragma unroll
    for (int c = 0; c < C_CLS; ++c) acc[c] = 0.f;
    for (int i = 0; i < 64; ++i) {
        int n = base + i;
        float hv = H1[n * H_HID + h];
        const float* sr = S1 + n * C_CLS;
        #pragma unroll
        for (int c = 0; c < C_CLS; ++c) acc[c] += sr[c] * hv;
    }
    #pragma unroll
    for (int c = 0; c < C_CLS; ++c) atomicAdd(&xp[c * H_HID + h], acc[c]);
}

// ---------------- K11: adjp[r] = S1^T @ (adj_r @ S1) ----------------
__global__ void k_adjp(const int* __restrict__ rowptr, const int* __restrict__ col,
                       const float* __restrict__ S1, float* __restrict__ adjp) {
    __shared__ float loc[R_REL * C_CLS * C_CLS];
    for (int i = threadIdx.x; i < R_REL * C_CLS * C_CLS; i += blockDim.x) loc[i] = 0.f;
    __syncthreads();
    int gidx = blockIdx.x * 16 + (threadIdx.x >> 4);   // (r, n) pair index
    int c = threadIdx.x & 15;
    int r = gidx / N_NODES, n = gidx - r * N_NODES;
    if (c < C_CLS) {
        float t = 0.f;
        int s = rowptr[r * (N_NODES + 1) + n], e2 = rowptr[r * (N_NODES + 1) + n + 1];
        const int* cr = col + r * E_EDGES;
        for (int idx = s; idx < e2; ++idx) t += S1[cr[idx] * C_CLS + c];
        const float* sn = S1 + n * C_CLS;
        #pragma unroll
        for (int k = 0; k < C_CLS; ++k) atomicAdd(&loc[(r * C_CLS + k) * C_CLS + c], sn[k] * t);
    }
    __syncthreads();
    for (int i = threadIdx.x; i < R_REL * C_CLS * C_CLS; i += blockDim.x) atomicAdd(&adjp[i], loc[i]);
}

// ---------------- K12: second cluster (tiny, one block) ----------------
__global__ void k_cluster2(const float* __restrict__ adjp, const float* __restrict__ xp,
                           const float* __restrict__ Ws2, float* __restrict__ out_x,
                           float* __restrict__ out_S2) {
    __shared__ float a2[C_CLS * C_CLS];
    __shared__ float xps[C_CLS * H_HID];
    __shared__ float y2[C_CLS * H_HID];
    __shared__ float lg[C_CLS * C_CLS];
    __shared__ float S2s[C_CLS * C_CLS];
    int t = threadIdx.x;   // 256 = H_HID
    for (int i = t; i < C_CLS * C_CLS; i += 256) a2[i] = adjp[i] + adjp[C_CLS * C_CLS + i];
    for (int i = t; i < C_CLS * H_HID; i += 256) xps[i] = xp[i];
    __syncthreads();
    for (int i = 0; i < C_CLS; ++i) {
        float acc = 0.f;
        #pragma unroll
        for (int j = 0; j < C_CLS; ++j) acc += a2[i * C_CLS + j] * xps[j * H_HID + t];
        y2[i * H_HID + t] = acc;
    }
    __syncthreads();
    for (int idx = t; idx < C_CLS * C_CLS; idx += 256) {
        int i = idx / C_CLS, c = idx % C_CLS;
        float acc = 0.f;
        for (int h = 0; h < H_HID; ++h) acc += y2[i * H_HID + h] * Ws2[h * C_CLS + c];
        lg[idx] = acc;
    }
    __syncthreads();
    if (t < C_CLS) {
        float m = -1e30f;
        for (int c = 0; c < C_CLS; ++c) m = fmaxf(m, lg[t * C_CLS + c]);
        float s = 0.f;
        for (int c = 0; c < C_CLS; ++c) { float ev = expf(lg[t * C_CLS + c] - m); S2s[t * C_CLS + c] = ev; s += ev; }
        for (int c = 0; c < C_CLS; ++c) { S2s[t * C_CLS + c] /= s; out_S2[t * C_CLS + c] = S2s[t * C_CLS + c]; }
    }
    __syncthreads();
    for (int c = 0; c < C_CLS; ++c) {
        float acc = 0.f;
        #pragma unroll
        for (int i = 0; i < C_CLS; ++i) acc += S2s[i * C_CLS + c] * xps[i * H_HID + t];
        out_x[c * H_HID + t] = acc;
    }
}

extern "C" void kernel_launch(void* const* d_in, const int* in_sizes, int n_in,
                              void* d_out, int out_size, void* d_ws, size_t ws_size,
                              hipStream_t stream) {
    const float* x_note  = (const float*)d_in[0];
    const int*   edges   = (const int*)d_in[1];
    const float* W_embed = (const float*)d_in[2];
    const float* b_embed = (const float*)d_in[3];
    const float* W_self  = (const float*)d_in[4];
    const float* W_neigh = (const float*)d_in[5];
    const float* b_gnn   = (const float*)d_in[6];
    const float* W_s1    = (const float*)d_in[7];
    const float* W_s2    = (const float*)d_in[8];
    float* out = (float*)d_out;

    // Output layout: x [15*256], S1 [8192*15], S2 [15*15]
    float* out_x  = out;
    float* out_S1 = out + C_CLS * H_HID;
    float* out_S2 = out + C_CLS * H_HID + N_NODES * C_CLS;

    // Workspace layout (region A 16MB is bitmap during CSR build, then H1+y)
    char* ws = (char*)d_ws;
    size_t off = 0;
    auto alloc = [&](size_t bytes) { size_t p = off; off += (bytes + 255) & ~(size_t)255; return p; };
    size_t regionA = alloc((size_t)16 * 1024 * 1024);
    size_t oX0     = alloc((size_t)N_NODES * D_EMB * 4);
    size_t oMsg    = alloc((size_t)R_REL * N_NODES * D_EMB * 4);
    size_t oCnt    = alloc((size_t)R_REL * N_NODES * 4);
    size_t oDeg    = alloc((size_t)R_REL * N_NODES * 4);
    size_t oCur    = alloc((size_t)R_REL * N_NODES * 4);
    size_t oRow    = alloc((size_t)R_REL * (N_NODES + 1) * 4);
    size_t oFlags  = alloc((size_t)R_REL * E_EDGES);
    size_t oCol    = alloc((size_t)R_REL * E_EDGES * 4);
    size_t oXp     = alloc((size_t)C_CLS * H_HID * 4);
    size_t oAdjp   = alloc((size_t)R_REL * C_CLS * C_CLS * 4);
    size_t total   = off;

    unsigned int*  bitmap = (unsigned int*)(ws + regionA);
    float*         H1     = (float*)(ws + regionA);                       // reuse after CSR build
    float*         y      = (float*)(ws + regionA + (size_t)8 * 1024 * 1024);
    float*         X0     = (float*)(ws + oX0);
    float*         msg    = (float*)(ws + oMsg);
    int*           cnt    = (int*)(ws + oCnt);
    int*           deg    = (int*)(ws + oDeg);
    int*           cur    = (int*)(ws + oCur);
    int*           rowptr = (int*)(ws + oRow);
    unsigned char* flags  = (unsigned char*)(ws + oFlags);
    int*           col    = (int*)(ws + oCol);
    float*         xp     = (float*)(ws + oXp);
    float*         adjp   = (float*)(ws + oAdjp);

    hipMemsetAsync(d_ws, 0, total, stream);

    k_embed<<<(N_NODES * D_EMB) / 256, 256, 0, stream>>>(x_note, W_embed, b_embed, X0);
    k_scatter<<<(R_REL * E_EDGES * 32) / 256, 256, 0, stream>>>(edges, X0, msg, cnt);
    k_flags<<<(R_REL * E_EDGES) / 256, 256, 0, stream>>>(edges, bitmap, flags, deg);
    k_scan<<<R_REL, 1024, 0, stream>>>(deg, rowptr);
    k_csr<<<(R_REL * E_EDGES) / 256, 256, 0, stream>>>(edges, flags, rowptr, cur, col);
    k_gnn<<<N_NODES, H_HID, 0, stream>>>(X0, msg, cnt, W_self, W_neigh, b_gnn, H1);
    k_spmm<<<N_NODES, H_HID, 0, stream>>>(rowptr, col, H1, y);
    k_softmax1<<<(N_NODES * 16) / 256, 256, 0, stream>>>(y, W_s1, out_S1);
    k_xp<<<N_NODES / 64, H_HID, 0, stream>>>(out_S1, H1, xp);
    k_adjp<<<(R_REL * N_NODES) / 16, 256, 0, stream>>>(rowptr, col, out_S1, adjp);
    k_cluster2<<<1, H_HID, 0, stream>>>(adjp, xp, W_s2, out_x, out_S2);
}